// Round 9
// baseline (444.029 us; speedup 1.0000x reference)
//
#include <hip/hip_runtime.h>
#include <hip/hip_bf16.h>
#include <stdint.h>

#define TT 8192   // tokens
#define HH 1024   // hidden
#define II 2048   // intermediate
#define EE 8      // experts
#define TOPK 2

typedef __bf16 bf16x8 __attribute__((ext_vector_type(8)));
typedef float f32x4 __attribute__((ext_vector_type(4)));
typedef unsigned short us8 __attribute__((ext_vector_type(8)));

__device__ __forceinline__ unsigned short f2bf(float f) {
  union { float f; unsigned int u; } c; c.f = f;
  unsigned int u = c.u;
  u += 0x7FFFu + ((u >> 16) & 1u);   // RNE
  return (unsigned short)(u >> 16);
}

__device__ __forceinline__ void gload_lds16(const void* g, void* l) {
  __builtin_amdgcn_global_load_lds((const __attribute__((address_space(1))) void*)g,
                                   (__attribute__((address_space(3))) void*)l, 16, 0, 0);
}

struct RouterSm {
  float wrt[8][1024];
  int lcount[8];
  int lbase[8];
  short ent_e[128];
  short ent_slot[128];
  float ent_g[128];
};
struct TransSm {
  float tile[64][65];
};

// ==== k_prep: fused {router | Wg,Wu->WguT interleaved | Wd->WdT} ====
// 1D grid: blocks 0..127 = router (dispatched first -> overlaps the
// BW-bound transpose blocks); 128.. = transpose tiles.
// WguT stored row s: gate col j=(s>>5)*16+(s&15) if (s>>4)&1==0, else up col j.
__global__ __launch_bounds__(256) void k_prep(
    const float* __restrict__ x, const float* __restrict__ Wr,
    const float* __restrict__ br,
    const float* __restrict__ Wg, const float* __restrict__ Wu,
    const float* __restrict__ Wd,
    unsigned short* __restrict__ xb,
    unsigned short* __restrict__ WguT, unsigned short* __restrict__ WdT,
    int* __restrict__ tlist, float* __restrict__ glist,
    int* __restrict__ counts) {
  __shared__ __align__(16) char smem[sizeof(RouterSm)];
  const int bid = blockIdx.x;
  const int tid = threadIdx.x;

  if (bid < 128) {
    // ---------------- router block ----------------
    RouterSm& R = *reinterpret_cast<RouterSm*>(smem);
    for (int i = tid; i < 8192; i += 256) R.wrt[i & 7][i >> 3] = Wr[i];
    if (tid < 8) R.lcount[tid] = 0;
    __syncthreads();
    int w = tid >> 6, l = tid & 63;
    int t0 = bid * 64;
    for (int it = 0; it < 16; ++it) {
      int t = t0 + w * 16 + it;
      const float4* xr = reinterpret_cast<const float4*>(x + (size_t)t * HH);
      float acc[8] = {0.f, 0.f, 0.f, 0.f, 0.f, 0.f, 0.f, 0.f};
#pragma unroll
      for (int j = 0; j < 4; ++j) {
        float4 xv = xr[j * 64 + l];
        int hbase = (j * 64 + l) * 4;
        ushort4 o;
        o.x = f2bf(xv.x); o.y = f2bf(xv.y); o.z = f2bf(xv.z); o.w = f2bf(xv.w);
        *reinterpret_cast<ushort4*>(xb + (size_t)t * HH + hbase) = o;
#pragma unroll
        for (int e = 0; e < 8; ++e) {
          float4 wv = *reinterpret_cast<const float4*>(&R.wrt[e][hbase]);
          acc[e] += xv.x * wv.x + xv.y * wv.y + xv.z * wv.z + xv.w * wv.w;
        }
      }
#pragma unroll
      for (int e = 0; e < 8; ++e)
#pragma unroll
        for (int off = 32; off > 0; off >>= 1) acc[e] += __shfl_xor(acc[e], off, 64);
      if (l == 0) {
        float lg[8];
#pragma unroll
        for (int e = 0; e < 8; ++e) lg[e] = acc[e] + br[e];
        int i0 = 0;
#pragma unroll
        for (int e = 1; e < 8; ++e) if (lg[e] > lg[i0]) i0 = e;
        int i1 = (i0 == 0) ? 1 : 0;
#pragma unroll
        for (int e = 0; e < 8; ++e) if (e != i0 && lg[e] > lg[i1]) i1 = e;
        float g0 = 1.f / (1.f + expf(-lg[i0]));
        float g1 = 1.f / (1.f + expf(-lg[i1]));
        float inv = 1.f / (g0 + g1 + 1e-10f);
        int idx = (w * 16 + it) * 2;
        int s0 = atomicAdd(&R.lcount[i0], 1);
        R.ent_e[idx] = (short)i0; R.ent_slot[idx] = (short)s0; R.ent_g[idx] = g0 * inv;
        int s1 = atomicAdd(&R.lcount[i1], 1);
        R.ent_e[idx + 1] = (short)i1; R.ent_slot[idx + 1] = (short)s1; R.ent_g[idx + 1] = g1 * inv;
      }
    }
    __syncthreads();
    if (tid < 8) R.lbase[tid] = atomicAdd(&counts[tid], R.lcount[tid]);
    __syncthreads();
    if (tid < 128) {
      int e = R.ent_e[tid];
      int slot = R.lbase[e] + R.ent_slot[tid];
      int t = t0 + (tid >> 1);
      tlist[e * TT + slot] = t;
      glist[e * TT + slot] = R.ent_g[tid];
    }
    return;
  }

  // ---------------- transpose block ----------------
  TransSm& T = *reinterpret_cast<TransSm*>(smem);
  const int tb = bid - 128;
  const int job = tb / 4096;          // 0=Wg, 1=Wu, 2=Wd
  const int rem = tb - job * 4096;
  const int e = rem >> 9;             // /512
  const int xt = rem & 511;
  const float* src; int C, r0, c0;
  if (job < 2) {   // Wg/Wu: [H][I]
    src = (job ? Wu : Wg) + (size_t)e * HH * II;
    C = II; c0 = (xt & 31) * 64; r0 = (xt >> 5) * 64;
  } else {         // Wd: [I][H]
    src = Wd + (size_t)e * II * HH;
    C = HH; c0 = (xt & 15) * 64; r0 = (xt >> 4) * 64;
  }
  const int tx = tid & 15, ty = tid >> 4;
#pragma unroll
  for (int i = 0; i < 4; ++i) {
    int rr = i * 16 + ty;
    float4 v = *reinterpret_cast<const float4*>(&src[(size_t)(r0 + rr) * C + c0 + tx * 4]);
    T.tile[rr][tx * 4 + 0] = v.x; T.tile[rr][tx * 4 + 1] = v.y;
    T.tile[rr][tx * 4 + 2] = v.z; T.tile[rr][tx * 4 + 3] = v.w;
  }
  __syncthreads();
#pragma unroll
  for (int i = 0; i < 2; ++i) {
    int idx = i * 256 + tid;
    int cc = idx >> 3, ch = idx & 7;   // out-row cc, 16B chunk ch
    us8 o;
#pragma unroll
    for (int j = 0; j < 8; ++j) o[j] = f2bf(T.tile[ch * 8 + j][cc]);
    if (job < 2) {
      int srow = c0 * 2 + ((cc >> 4) << 5) + job * 16 + (cc & 15);
      *reinterpret_cast<us8*>(&WguT[((size_t)e * 2 * II + srow) * HH + r0 + ch * 8]) = o;
    } else {
      *reinterpret_cast<us8*>(&WdT[((size_t)e * HH + c0 + cc) * II + r0 + ch * 8]) = o;
    }
  }
}

// ---------------- GEMM1: 128x128 vs interleaved WguT ----------------
// R6-proven 2-barrier structure, 4 blocks/CU. Grid swapped (x = M-tile
// fastest, y = N-tile): consecutive co-resident blocks share the same
// 256KB B-panel -> B reuse hits L2 instead of HBM re-fetch.
// Epilogue: acc[m][n] n even = gate, n+1 = up of SAME logical cols.
__global__ __launch_bounds__(256, 4) void k_gemm1(
    const unsigned short* __restrict__ xb,
    const unsigned short* __restrict__ WguT,
    const int* __restrict__ tlist, const float* __restrict__ glist,
    const int* __restrict__ counts,
    unsigned short* __restrict__ hbuf) {
  __shared__ unsigned short lsA[128 * 64];
  __shared__ unsigned short lsB[128 * 64];
  __shared__ int s_tok[128];
  __shared__ float s_gate[128];

  const int e = blockIdx.z;
  int n_e = 0, obase = 0;
#pragma unroll
  for (int q = 0; q < EE; ++q) {   // inline prefix (kills k_offsets dispatch)
    int c = counts[q];
    if (q < e) obase += c;
    if (q == e) n_e = c;
  }
  const int row0 = blockIdx.x * 128;
  if (row0 >= n_e) return;
  const int n0 = blockIdx.y * 128;   // stored-row base in WguT
  const int tid = threadIdx.x;

  if (tid < 128) {
    int r = row0 + tid;
    int tok = 0; float gt = 0.f;
    if (r < n_e) { tok = tlist[e * TT + r]; gt = glist[e * TT + r]; }
    s_tok[tid] = tok; s_gate[tid] = gt;
  }
  __syncthreads();

  const int scol = (tid & 7) ^ ((tid >> 3) & 7);
  const unsigned short* srcA[4];
  const unsigned short* srcB[4];
#pragma unroll
  for (int i = 0; i < 4; ++i) {
    int row = i * 32 + (tid >> 3);
    srcA[i] = xb + (size_t)s_tok[row] * HH + scol * 8;
    srcB[i] = WguT + ((size_t)e * 2 * II + n0 + row) * HH + scol * 8;
  }

  f32x4 zero = {0.f, 0.f, 0.f, 0.f};
  f32x4 acc[4][4];
#pragma unroll
  for (int m = 0; m < 4; ++m)
#pragma unroll
    for (int n = 0; n < 4; ++n) acc[m][n] = zero;

  const int l = tid & 63;
  const int w = tid >> 6;
  const int wr = (w >> 1) * 64;
  const int wc = (w & 1) * 64;
  const int lrow = l & 15;
  const int lk = l >> 4;
  const int swz = (l & 7) << 4;
  const int aoff0 = (wr + lrow) * 128 + lk * 16;
  const int boff0 = (wc + lrow) * 128 + lk * 16;
  const char* lcA = (const char*)lsA;
  const char* lcB = (const char*)lsB;

  for (int kt = 0; kt < HH / 64; ++kt) {
#pragma unroll
    for (int i = 0; i < 4; ++i) {
      gload_lds16(srcA[i] + kt * 64, (char*)lsA + i * 4096 + tid * 16);
      gload_lds16(srcB[i] + kt * 64, (char*)lsB + i * 4096 + tid * 16);
    }
    __syncthreads();
#pragma unroll
    for (int kk = 0; kk < 2; ++kk) {
      bf16x8 af[4], bf[4];
#pragma unroll
      for (int m = 0; m < 4; ++m)
        af[m] = *(const bf16x8*)(lcA + ((aoff0 + m * 2048 + kk * 64) ^ swz));
#pragma unroll
      for (int n = 0; n < 4; ++n)
        bf[n] = *(const bf16x8*)(lcB + ((boff0 + n * 2048 + kk * 64) ^ swz));
#pragma unroll
      for (int m = 0; m < 4; ++m)
#pragma unroll
        for (int n = 0; n < 4; ++n)
          acc[m][n] = __builtin_amdgcn_mfma_f32_16x16x32_bf16(af[m], bf[n], acc[m][n], 0, 0, 0);
    }
    __syncthreads();
  }

#pragma unroll
  for (int m = 0; m < 4; ++m)
#pragma unroll
    for (int n = 0; n < 4; n += 2)   // n = gate frag, n+1 = up frag (same cols)
#pragma unroll
      for (int r = 0; r < 4; ++r) {
        int rl = wr + m * 16 + lk * 4 + r;   // C/D: col=lane&15, row=(lane>>4)*4+reg
        if (row0 + rl < n_e) {
          float gv = acc[m][n][r];
          float uv = acc[m][n + 1][r];
          float val = gv / (1.f + __expf(-gv)) * uv * s_gate[rl];
          int L = (n0 >> 1) + (wc >> 1) + (n >> 1) * 16 + lrow;   // logical II col
          hbuf[(size_t)(obase + row0 + rl) * II + L] = f2bf(val);
        }
      }
}

// ---------------- GEMM2: out += h @ Wd (atomic scatter; grid swapped) ----------------
__global__ __launch_bounds__(256, 4) void k_gemm2(
    const unsigned short* __restrict__ hbuf,
    const unsigned short* __restrict__ WdT,   // [E][H][I] (k=I contiguous)
    const int* __restrict__ tlist,
    const int* __restrict__ counts,
    float* __restrict__ out) {
  __shared__ unsigned short lsA[128 * 64];
  __shared__ unsigned short lsB[128 * 64];
  __shared__ int s_tok[128];

  const int e = blockIdx.z;
  int n_e = 0, obase = 0;
#pragma unroll
  for (int q = 0; q < EE; ++q) {
    int c = counts[q];
    if (q < e) obase += c;
    if (q == e) n_e = c;
  }
  const int row0 = blockIdx.x * 128;
  if (row0 >= n_e) return;
  const int n0 = blockIdx.y * 128;   // H columns
  const int tid = threadIdx.x;

  if (tid < 128) {
    int r = row0 + tid;
    s_tok[tid] = (r < n_e) ? tlist[e * TT + r] : 0;
  }
  __syncthreads();

  const int scol = (tid & 7) ^ ((tid >> 3) & 7);
  const unsigned short* srcA[4];
  const unsigned short* srcB[4];
#pragma unroll
  for (int i = 0; i < 4; ++i) {
    int row = i * 32 + (tid >> 3);
    int ar = obase + row0 + row;
    if (ar > TT * TOPK - 1) ar = TT * TOPK - 1;   // clamp pad rows inside hbuf
    srcA[i] = hbuf + (size_t)ar * II + scol * 8;
    srcB[i] = WdT + ((size_t)e * HH + n0 + row) * II + scol * 8;
  }

  f32x4 zero = {0.f, 0.f, 0.f, 0.f};
  f32x4 acc[4][4];
#pragma unroll
  for (int m = 0; m < 4; ++m)
#pragma unroll
    for (int n = 0; n < 4; ++n) acc[m][n] = zero;

  const int l = tid & 63;
  const int w = tid >> 6;
  const int wr = (w >> 1) * 64;
  const int wc = (w & 1) * 64;
  const int lrow = l & 15;
  const int lk = l >> 4;
  const int swz = (l & 7) << 4;
  const int aoff0 = (wr + lrow) * 128 + lk * 16;
  const int boff0 = (wc + lrow) * 128 + lk * 16;
  const char* lcA = (const char*)lsA;
  const char* lcB = (const char*)lsB;

  for (int kt = 0; kt < II / 64; ++kt) {
#pragma unroll
    for (int i = 0; i < 4; ++i) {
      gload_lds16(srcA[i] + kt * 64, (char*)lsA + i * 4096 + tid * 16);
      gload_lds16(srcB[i] + kt * 64, (char*)lsB + i * 4096 + tid * 16);
    }
    __syncthreads();
#pragma unroll
    for (int kk = 0; kk < 2; ++kk) {
      bf16x8 af[4], bf[4];
#pragma unroll
      for (int m = 0; m < 4; ++m)
        af[m] = *(const bf16x8*)(lcA + ((aoff0 + m * 2048 + kk * 64) ^ swz));
#pragma unroll
      for (int n = 0; n < 4; ++n)
        bf[n] = *(const bf16x8*)(lcB + ((boff0 + n * 2048 + kk * 64) ^ swz));
#pragma unroll
      for (int m = 0; m < 4; ++m)
#pragma unroll
        for (int n = 0; n < 4; ++n)
          acc[m][n] = __builtin_amdgcn_mfma_f32_16x16x32_bf16(af[m], bf[n], acc[m][n], 0, 0, 0);
    }
    __syncthreads();
  }

#pragma unroll
  for (int m = 0; m < 4; ++m)
#pragma unroll
    for (int n = 0; n < 4; ++n)
#pragma unroll
      for (int r = 0; r < 4; ++r) {
        int rl = wr + m * 16 + lk * 4 + r;
        if (row0 + rl < n_e) {
          int t = s_tok[rl];
          unsafeAtomicAdd(&out[(size_t)t * HH + n0 + wc + n * 16 + lrow], acc[m][n][r]);
        }
      }
}

extern "C" void kernel_launch(void* const* d_in, const int* in_sizes, int n_in,
                              void* d_out, int out_size, void* d_ws, size_t ws_size,
                              hipStream_t stream) {
  const float* x  = (const float*)d_in[0];
  const float* Wr = (const float*)d_in[1];
  const float* br = (const float*)d_in[2];
  const float* Wg = (const float*)d_in[3];
  const float* Wu = (const float*)d_in[4];
  const float* Wd = (const float*)d_in[5];
  float* out = (float*)d_out;

  char* ws = (char*)d_ws;
  size_t off = 0;
  auto alloc = [&](size_t bytes) {
    char* p = ws + off;
    off += (bytes + 255) & ~(size_t)255;
    return p;
  };
  unsigned short* xb   = (unsigned short*)alloc((size_t)TT * HH * 2);            // 16 MB
  unsigned short* WguT = (unsigned short*)alloc((size_t)EE * 2 * II * HH * 2);   // 64 MB
  unsigned short* WdT  = (unsigned short*)alloc((size_t)EE * HH * II * 2);       // 32 MB
  unsigned short* hbuf = (unsigned short*)alloc((size_t)TT * TOPK * II * 2);     // 64 MB
  int*   tlist  = (int*)alloc((size_t)EE * TT * 4);
  float* glist  = (float*)alloc((size_t)EE * TT * 4);
  int*   counts = (int*)alloc(128);

  hipMemsetAsync(counts, 0, 128, stream);
  hipMemsetAsync(d_out, 0, (size_t)TT * HH * 4, stream);

  // fused prep: router (blocks 0..127, overlaps) + Wg/Wu/Wd transposes
  k_prep<<<128 + 3 * EE * 512, 256, 0, stream>>>(x, Wr, br, Wg, Wu, Wd,
                                                 xb, WguT, WdT, tlist, glist, counts);

  dim3 g1(TT / 128, 2 * II / 128, EE);   // x = M-tile fastest (B-panel L2 reuse)
  k_gemm1<<<g1, 256, 0, stream>>>(xb, WguT, tlist, glist, counts, hbuf);
  dim3 g2(TT / 128, HH / 128, EE);
  k_gemm2<<<g2, 256, 0, stream>>>(hbuf, WdT, tlist, counts, out);

  (void)in_sizes; (void)n_in; (void)out_size; (void)ws_size;
}

// Round 10
// 354.050 us; speedup vs baseline: 1.2541x; 1.2541x over previous
//
#include <hip/hip_runtime.h>
#include <hip/hip_bf16.h>
#include <stdint.h>

#define TT 8192   // tokens
#define HH 1024   // hidden
#define II 2048   // intermediate
#define EE 8      // experts
#define TOPK 2

typedef __bf16 bf16x8 __attribute__((ext_vector_type(8)));
typedef float f32x4 __attribute__((ext_vector_type(4)));
typedef unsigned short us8 __attribute__((ext_vector_type(8)));

__device__ __forceinline__ unsigned short f2bf(float f) {
  union { float f; unsigned int u; } c; c.f = f;
  unsigned int u = c.u;
  u += 0x7FFFu + ((u >> 16) & 1u);   // RNE
  return (unsigned short)(u >> 16);
}

__device__ __forceinline__ void gload_lds16(const void* g, void* l) {
  __builtin_amdgcn_global_load_lds((const __attribute__((address_space(1))) void*)g,
                                   (__attribute__((address_space(3))) void*)l, 16, 0, 0);
}

struct RouterSm {
  float wrt[8][1024];
  int lcount[8];
  int lbase[8];
  short ent_e[128];
  short ent_slot[128];
  float ent_g[128];
};
struct TransSm {
  float tile[64][65];
};

// ==== k_prep: fused {router | Wg,Wu->WguT interleaved | Wd->WdT} ====
// 1D grid: blocks 0..127 = router (dispatched first -> overlaps the
// BW-bound transpose blocks); 128.. = transpose tiles.
// WguT stored row s: gate col j=(s>>5)*16+(s&15) if (s>>4)&1==0, else up col j.
__global__ __launch_bounds__(256) void k_prep(
    const float* __restrict__ x, const float* __restrict__ Wr,
    const float* __restrict__ br,
    const float* __restrict__ Wg, const float* __restrict__ Wu,
    const float* __restrict__ Wd,
    unsigned short* __restrict__ xb,
    unsigned short* __restrict__ WguT, unsigned short* __restrict__ WdT,
    int* __restrict__ tlist, float* __restrict__ glist,
    int* __restrict__ counts) {
  __shared__ __align__(16) char smem[sizeof(RouterSm)];
  const int bid = blockIdx.x;
  const int tid = threadIdx.x;

  if (bid < 128) {
    // ---------------- router block ----------------
    RouterSm& R = *reinterpret_cast<RouterSm*>(smem);
    for (int i = tid; i < 8192; i += 256) R.wrt[i & 7][i >> 3] = Wr[i];
    if (tid < 8) R.lcount[tid] = 0;
    __syncthreads();
    int w = tid >> 6, l = tid & 63;
    int t0 = bid * 64;
    for (int it = 0; it < 16; ++it) {
      int t = t0 + w * 16 + it;
      const float4* xr = reinterpret_cast<const float4*>(x + (size_t)t * HH);
      float acc[8] = {0.f, 0.f, 0.f, 0.f, 0.f, 0.f, 0.f, 0.f};
#pragma unroll
      for (int j = 0; j < 4; ++j) {
        float4 xv = xr[j * 64 + l];
        int hbase = (j * 64 + l) * 4;
        ushort4 o;
        o.x = f2bf(xv.x); o.y = f2bf(xv.y); o.z = f2bf(xv.z); o.w = f2bf(xv.w);
        *reinterpret_cast<ushort4*>(xb + (size_t)t * HH + hbase) = o;
#pragma unroll
        for (int e = 0; e < 8; ++e) {
          float4 wv = *reinterpret_cast<const float4*>(&R.wrt[e][hbase]);
          acc[e] += xv.x * wv.x + xv.y * wv.y + xv.z * wv.z + xv.w * wv.w;
        }
      }
#pragma unroll
      for (int e = 0; e < 8; ++e)
#pragma unroll
        for (int off = 32; off > 0; off >>= 1) acc[e] += __shfl_xor(acc[e], off, 64);
      if (l == 0) {
        float lg[8];
#pragma unroll
        for (int e = 0; e < 8; ++e) lg[e] = acc[e] + br[e];
        int i0 = 0;
#pragma unroll
        for (int e = 1; e < 8; ++e) if (lg[e] > lg[i0]) i0 = e;
        int i1 = (i0 == 0) ? 1 : 0;
#pragma unroll
        for (int e = 0; e < 8; ++e) if (e != i0 && lg[e] > lg[i1]) i1 = e;
        float g0 = 1.f / (1.f + expf(-lg[i0]));
        float g1 = 1.f / (1.f + expf(-lg[i1]));
        float inv = 1.f / (g0 + g1 + 1e-10f);
        int idx = (w * 16 + it) * 2;
        int s0 = atomicAdd(&R.lcount[i0], 1);
        R.ent_e[idx] = (short)i0; R.ent_slot[idx] = (short)s0; R.ent_g[idx] = g0 * inv;
        int s1 = atomicAdd(&R.lcount[i1], 1);
        R.ent_e[idx + 1] = (short)i1; R.ent_slot[idx + 1] = (short)s1; R.ent_g[idx + 1] = g1 * inv;
      }
    }
    __syncthreads();
    if (tid < 8) R.lbase[tid] = atomicAdd(&counts[tid], R.lcount[tid]);
    __syncthreads();
    if (tid < 128) {
      int e = R.ent_e[tid];
      int slot = R.lbase[e] + R.ent_slot[tid];
      int t = t0 + (tid >> 1);
      tlist[e * TT + slot] = t;
      glist[e * TT + slot] = R.ent_g[tid];
    }
    return;
  }

  // ---------------- transpose block ----------------
  TransSm& T = *reinterpret_cast<TransSm*>(smem);
  const int tb = bid - 128;
  const int job = tb / 4096;          // 0=Wg, 1=Wu, 2=Wd
  const int rem = tb - job * 4096;
  const int e = rem >> 9;             // /512
  const int xt = rem & 511;
  const float* src; int C, r0, c0;
  if (job < 2) {   // Wg/Wu: [H][I]
    src = (job ? Wu : Wg) + (size_t)e * HH * II;
    C = II; c0 = (xt & 31) * 64; r0 = (xt >> 5) * 64;
  } else {         // Wd: [I][H]
    src = Wd + (size_t)e * II * HH;
    C = HH; c0 = (xt & 15) * 64; r0 = (xt >> 4) * 64;
  }
  const int tx = tid & 15, ty = tid >> 4;
#pragma unroll
  for (int i = 0; i < 4; ++i) {
    int rr = i * 16 + ty;
    float4 v = *reinterpret_cast<const float4*>(&src[(size_t)(r0 + rr) * C + c0 + tx * 4]);
    T.tile[rr][tx * 4 + 0] = v.x; T.tile[rr][tx * 4 + 1] = v.y;
    T.tile[rr][tx * 4 + 2] = v.z; T.tile[rr][tx * 4 + 3] = v.w;
  }
  __syncthreads();
#pragma unroll
  for (int i = 0; i < 2; ++i) {
    int idx = i * 256 + tid;
    int cc = idx >> 3, ch = idx & 7;   // out-row cc, 16B chunk ch
    us8 o;
#pragma unroll
    for (int j = 0; j < 8; ++j) o[j] = f2bf(T.tile[ch * 8 + j][cc]);
    if (job < 2) {
      int srow = c0 * 2 + ((cc >> 4) << 5) + job * 16 + (cc & 15);
      *reinterpret_cast<us8*>(&WguT[((size_t)e * 2 * II + srow) * HH + r0 + ch * 8]) = o;
    } else {
      *reinterpret_cast<us8*>(&WdT[((size_t)e * HH + c0 + cc) * II + r0 + ch * 8]) = o;
    }
  }
}

// ---------------- GEMM1: 128x128 vs interleaved WguT ----------------
// R6/R8-proven 2-barrier structure, 4 blocks/CU, grid: x = N-tile fastest
// (consecutive blocks share the A-tile; B-panel reuse via L3 — R8-measured
// best ordering; R9's swap regressed 1.7x). Inline prefix-sum from counts.
// Epilogue: acc[m][n] n even = gate, n+1 = up of SAME logical cols.
__global__ __launch_bounds__(256, 4) void k_gemm1(
    const unsigned short* __restrict__ xb,
    const unsigned short* __restrict__ WguT,
    const int* __restrict__ tlist, const float* __restrict__ glist,
    const int* __restrict__ counts,
    unsigned short* __restrict__ hbuf) {
  __shared__ unsigned short lsA[128 * 64];
  __shared__ unsigned short lsB[128 * 64];
  __shared__ int s_tok[128];
  __shared__ float s_gate[128];

  const int e = blockIdx.z;
  int n_e = 0, obase = 0;
#pragma unroll
  for (int q = 0; q < EE; ++q) {   // inline prefix (no k_offsets dispatch)
    int c = counts[q];
    if (q < e) obase += c;
    if (q == e) n_e = c;
  }
  const int row0 = blockIdx.y * 128;
  if (row0 >= n_e) return;
  const int n0 = blockIdx.x * 128;   // stored-row base in WguT
  const int tid = threadIdx.x;

  if (tid < 128) {
    int r = row0 + tid;
    int tok = 0; float gt = 0.f;
    if (r < n_e) { tok = tlist[e * TT + r]; gt = glist[e * TT + r]; }
    s_tok[tid] = tok; s_gate[tid] = gt;
  }
  __syncthreads();

  const int scol = (tid & 7) ^ ((tid >> 3) & 7);
  const unsigned short* srcA[4];
  const unsigned short* srcB[4];
#pragma unroll
  for (int i = 0; i < 4; ++i) {
    int row = i * 32 + (tid >> 3);
    srcA[i] = xb + (size_t)s_tok[row] * HH + scol * 8;
    srcB[i] = WguT + ((size_t)e * 2 * II + n0 + row) * HH + scol * 8;
  }

  f32x4 zero = {0.f, 0.f, 0.f, 0.f};
  f32x4 acc[4][4];
#pragma unroll
  for (int m = 0; m < 4; ++m)
#pragma unroll
    for (int n = 0; n < 4; ++n) acc[m][n] = zero;

  const int l = tid & 63;
  const int w = tid >> 6;
  const int wr = (w >> 1) * 64;
  const int wc = (w & 1) * 64;
  const int lrow = l & 15;
  const int lk = l >> 4;
  const int swz = (l & 7) << 4;
  const int aoff0 = (wr + lrow) * 128 + lk * 16;
  const int boff0 = (wc + lrow) * 128 + lk * 16;
  const char* lcA = (const char*)lsA;
  const char* lcB = (const char*)lsB;

  for (int kt = 0; kt < HH / 64; ++kt) {
#pragma unroll
    for (int i = 0; i < 4; ++i) {
      gload_lds16(srcA[i] + kt * 64, (char*)lsA + i * 4096 + tid * 16);
      gload_lds16(srcB[i] + kt * 64, (char*)lsB + i * 4096 + tid * 16);
    }
    __syncthreads();
#pragma unroll
    for (int kk = 0; kk < 2; ++kk) {
      bf16x8 af[4], bf[4];
#pragma unroll
      for (int m = 0; m < 4; ++m)
        af[m] = *(const bf16x8*)(lcA + ((aoff0 + m * 2048 + kk * 64) ^ swz));
#pragma unroll
      for (int n = 0; n < 4; ++n)
        bf[n] = *(const bf16x8*)(lcB + ((boff0 + n * 2048 + kk * 64) ^ swz));
#pragma unroll
      for (int m = 0; m < 4; ++m)
#pragma unroll
        for (int n = 0; n < 4; ++n)
          acc[m][n] = __builtin_amdgcn_mfma_f32_16x16x32_bf16(af[m], bf[n], acc[m][n], 0, 0, 0);
    }
    __syncthreads();
  }

#pragma unroll
  for (int m = 0; m < 4; ++m)
#pragma unroll
    for (int n = 0; n < 4; n += 2)   // n = gate frag, n+1 = up frag (same cols)
#pragma unroll
      for (int r = 0; r < 4; ++r) {
        int rl = wr + m * 16 + lk * 4 + r;   // C/D: col=lane&15, row=(lane>>4)*4+reg
        if (row0 + rl < n_e) {
          float gv = acc[m][n][r];
          float uv = acc[m][n + 1][r];
          float val = gv / (1.f + __expf(-gv)) * uv * s_gate[rl];
          int L = (n0 >> 1) + (wc >> 1) + (n >> 1) * 16 + lrow;   // logical II col
          hbuf[(size_t)(obase + row0 + rl) * II + L] = f2bf(val);
        }
      }
}

// ---------------- GEMM2: out += h @ Wd (atomic scatter; R8 grid order) ----------------
__global__ __launch_bounds__(256, 4) void k_gemm2(
    const unsigned short* __restrict__ hbuf,
    const unsigned short* __restrict__ WdT,   // [E][H][I] (k=I contiguous)
    const int* __restrict__ tlist,
    const int* __restrict__ counts,
    float* __restrict__ out) {
  __shared__ unsigned short lsA[128 * 64];
  __shared__ unsigned short lsB[128 * 64];
  __shared__ int s_tok[128];

  const int e = blockIdx.z;
  int n_e = 0, obase = 0;
#pragma unroll
  for (int q = 0; q < EE; ++q) {
    int c = counts[q];
    if (q < e) obase += c;
    if (q == e) n_e = c;
  }
  const int row0 = blockIdx.y * 128;
  if (row0 >= n_e) return;
  const int n0 = blockIdx.x * 128;   // H columns
  const int tid = threadIdx.x;

  if (tid < 128) {
    int r = row0 + tid;
    s_tok[tid] = (r < n_e) ? tlist[e * TT + r] : 0;
  }
  __syncthreads();

  const int scol = (tid & 7) ^ ((tid >> 3) & 7);
  const unsigned short* srcA[4];
  const unsigned short* srcB[4];
#pragma unroll
  for (int i = 0; i < 4; ++i) {
    int row = i * 32 + (tid >> 3);
    int ar = obase + row0 + row;
    if (ar > TT * TOPK - 1) ar = TT * TOPK - 1;   // clamp pad rows inside hbuf
    srcA[i] = hbuf + (size_t)ar * II + scol * 8;
    srcB[i] = WdT + ((size_t)e * HH + n0 + row) * II + scol * 8;
  }

  f32x4 zero = {0.f, 0.f, 0.f, 0.f};
  f32x4 acc[4][4];
#pragma unroll
  for (int m = 0; m < 4; ++m)
#pragma unroll
    for (int n = 0; n < 4; ++n) acc[m][n] = zero;

  const int l = tid & 63;
  const int w = tid >> 6;
  const int wr = (w >> 1) * 64;
  const int wc = (w & 1) * 64;
  const int lrow = l & 15;
  const int lk = l >> 4;
  const int swz = (l & 7) << 4;
  const int aoff0 = (wr + lrow) * 128 + lk * 16;
  const int boff0 = (wc + lrow) * 128 + lk * 16;
  const char* lcA = (const char*)lsA;
  const char* lcB = (const char*)lsB;

  for (int kt = 0; kt < II / 64; ++kt) {
#pragma unroll
    for (int i = 0; i < 4; ++i) {
      gload_lds16(srcA[i] + kt * 64, (char*)lsA + i * 4096 + tid * 16);
      gload_lds16(srcB[i] + kt * 64, (char*)lsB + i * 4096 + tid * 16);
    }
    __syncthreads();
#pragma unroll
    for (int kk = 0; kk < 2; ++kk) {
      bf16x8 af[4], bf[4];
#pragma unroll
      for (int m = 0; m < 4; ++m)
        af[m] = *(const bf16x8*)(lcA + ((aoff0 + m * 2048 + kk * 64) ^ swz));
#pragma unroll
      for (int n = 0; n < 4; ++n)
        bf[n] = *(const bf16x8*)(lcB + ((boff0 + n * 2048 + kk * 64) ^ swz));
#pragma unroll
      for (int m = 0; m < 4; ++m)
#pragma unroll
        for (int n = 0; n < 4; ++n)
          acc[m][n] = __builtin_amdgcn_mfma_f32_16x16x32_bf16(af[m], bf[n], acc[m][n], 0, 0, 0);
    }
    __syncthreads();
  }

#pragma unroll
  for (int m = 0; m < 4; ++m)
#pragma unroll
    for (int n = 0; n < 4; ++n)
#pragma unroll
      for (int r = 0; r < 4; ++r) {
        int rl = wr + m * 16 + lk * 4 + r;
        if (row0 + rl < n_e) {
          int t = s_tok[rl];
          unsafeAtomicAdd(&out[(size_t)t * HH + n0 + wc + n * 16 + lrow], acc[m][n][r]);
        }
      }
}

extern "C" void kernel_launch(void* const* d_in, const int* in_sizes, int n_in,
                              void* d_out, int out_size, void* d_ws, size_t ws_size,
                              hipStream_t stream) {
  const float* x  = (const float*)d_in[0];
  const float* Wr = (const float*)d_in[1];
  const float* br = (const float*)d_in[2];
  const float* Wg = (const float*)d_in[3];
  const float* Wu = (const float*)d_in[4];
  const float* Wd = (const float*)d_in[5];
  float* out = (float*)d_out;

  char* ws = (char*)d_ws;
  size_t off = 0;
  auto alloc = [&](size_t bytes) {
    char* p = ws + off;
    off += (bytes + 255) & ~(size_t)255;
    return p;
  };
  unsigned short* xb   = (unsigned short*)alloc((size_t)TT * HH * 2);            // 16 MB
  unsigned short* WguT = (unsigned short*)alloc((size_t)EE * 2 * II * HH * 2);   // 64 MB
  unsigned short* WdT  = (unsigned short*)alloc((size_t)EE * HH * II * 2);       // 32 MB
  unsigned short* hbuf = (unsigned short*)alloc((size_t)TT * TOPK * II * 2);     // 64 MB
  int*   tlist  = (int*)alloc((size_t)EE * TT * 4);
  float* glist  = (float*)alloc((size_t)EE * TT * 4);
  int*   counts = (int*)alloc(128);

  hipMemsetAsync(counts, 0, 128, stream);
  hipMemsetAsync(d_out, 0, (size_t)TT * HH * 4, stream);

  // fused prep: router (blocks 0..127, overlaps) + Wg/Wu/Wd transposes
  k_prep<<<128 + 3 * EE * 512, 256, 0, stream>>>(x, Wr, br, Wg, Wu, Wd,
                                                 xb, WguT, WdT, tlist, glist, counts);

  dim3 g1(2 * II / 128, TT / 128, EE);   // x = N-tile fastest (R8-proven order)
  k_gemm1<<<g1, 256, 0, stream>>>(xb, WguT, tlist, glist, counts, hbuf);
  dim3 g2(HH / 128, TT / 128, EE);
  k_gemm2<<<g2, 256, 0, stream>>>(hbuf, WdT, tlist, counts, out);

  (void)in_sizes; (void)n_in; (void)out_size; (void)ws_size;
}

// Round 11
// 345.153 us; speedup vs baseline: 1.2865x; 1.0258x over previous
//
#include <hip/hip_runtime.h>
#include <hip/hip_bf16.h>
#include <stdint.h>

#define TT 8192   // tokens
#define HH 1024   // hidden
#define II 2048   // intermediate
#define EE 8      // experts
#define TOPK 2

typedef __bf16 bf16x8 __attribute__((ext_vector_type(8)));
typedef float f32x4 __attribute__((ext_vector_type(4)));
typedef unsigned short us8 __attribute__((ext_vector_type(8)));

__device__ __forceinline__ unsigned short f2bf(float f) {
  union { float f; unsigned int u; } c; c.f = f;
  unsigned int u = c.u;
  u += 0x7FFFu + ((u >> 16) & 1u);   // RNE
  return (unsigned short)(u >> 16);
}

__device__ __forceinline__ void gload_lds16(const void* g, void* l) {
  __builtin_amdgcn_global_load_lds((const __attribute__((address_space(1))) void*)g,
                                   (__attribute__((address_space(3))) void*)l, 16, 0, 0);
}

struct RouterSm {
  float wrt[8][1024];
  int lcount[8];
  int lbase[8];
  short ent_e[128];
  short ent_slot[128];
  float ent_g[128];
};
struct TransSm {
  float tile[64][65];
};

// ==== k_prep: fused {router | Wg,Wu->WguT | Wd->WdT | zero d_out} ====
// 1D grid: blocks 0..127 router; 128..12415 transpose; 12416..12927 zero-out.
// WguT stored row s: gate col j=(s>>5)*16+(s&15) if (s>>4)&1==0, else up col j.
#define NTRANS (3 * EE * 512)
#define NZERO 512
__global__ __launch_bounds__(256) void k_prep(
    const float* __restrict__ x, const float* __restrict__ Wr,
    const float* __restrict__ br,
    const float* __restrict__ Wg, const float* __restrict__ Wu,
    const float* __restrict__ Wd,
    unsigned short* __restrict__ xb,
    unsigned short* __restrict__ WguT, unsigned short* __restrict__ WdT,
    int* __restrict__ tlist, float* __restrict__ glist,
    int* __restrict__ counts, float* __restrict__ outz) {
  __shared__ __align__(16) char smem[sizeof(RouterSm)];
  const int bid = blockIdx.x;
  const int tid = threadIdx.x;

  if (bid >= 128 + NTRANS) {
    // ---------------- zero d_out block (64 KB each) ----------------
    const int zb = bid - 128 - NTRANS;
    float4 z = {0.f, 0.f, 0.f, 0.f};
    float4* dst = reinterpret_cast<float4*>(outz) + (size_t)zb * 4096 + tid;
#pragma unroll
    for (int i = 0; i < 16; ++i) dst[i * 256] = z;
    return;
  }

  if (bid < 128) {
    // ---------------- router block ----------------
    RouterSm& R = *reinterpret_cast<RouterSm*>(smem);
    for (int i = tid; i < 8192; i += 256) R.wrt[i & 7][i >> 3] = Wr[i];
    if (tid < 8) R.lcount[tid] = 0;
    __syncthreads();
    int w = tid >> 6, l = tid & 63;
    int t0 = bid * 64;
    for (int it = 0; it < 16; ++it) {
      int t = t0 + w * 16 + it;
      const float4* xr = reinterpret_cast<const float4*>(x + (size_t)t * HH);
      float acc[8] = {0.f, 0.f, 0.f, 0.f, 0.f, 0.f, 0.f, 0.f};
#pragma unroll
      for (int j = 0; j < 4; ++j) {
        float4 xv = xr[j * 64 + l];
        int hbase = (j * 64 + l) * 4;
        ushort4 o;
        o.x = f2bf(xv.x); o.y = f2bf(xv.y); o.z = f2bf(xv.z); o.w = f2bf(xv.w);
        *reinterpret_cast<ushort4*>(xb + (size_t)t * HH + hbase) = o;
#pragma unroll
        for (int e = 0; e < 8; ++e) {
          float4 wv = *reinterpret_cast<const float4*>(&R.wrt[e][hbase]);
          acc[e] += xv.x * wv.x + xv.y * wv.y + xv.z * wv.z + xv.w * wv.w;
        }
      }
#pragma unroll
      for (int e = 0; e < 8; ++e)
#pragma unroll
        for (int off = 32; off > 0; off >>= 1) acc[e] += __shfl_xor(acc[e], off, 64);
      if (l == 0) {
        float lg[8];
#pragma unroll
        for (int e = 0; e < 8; ++e) lg[e] = acc[e] + br[e];
        int i0 = 0;
#pragma unroll
        for (int e = 1; e < 8; ++e) if (lg[e] > lg[i0]) i0 = e;
        int i1 = (i0 == 0) ? 1 : 0;
#pragma unroll
        for (int e = 0; e < 8; ++e) if (e != i0 && lg[e] > lg[i1]) i1 = e;
        float g0 = 1.f / (1.f + expf(-lg[i0]));
        float g1 = 1.f / (1.f + expf(-lg[i1]));
        float inv = 1.f / (g0 + g1 + 1e-10f);
        int idx = (w * 16 + it) * 2;
        int s0 = atomicAdd(&R.lcount[i0], 1);
        R.ent_e[idx] = (short)i0; R.ent_slot[idx] = (short)s0; R.ent_g[idx] = g0 * inv;
        int s1 = atomicAdd(&R.lcount[i1], 1);
        R.ent_e[idx + 1] = (short)i1; R.ent_slot[idx + 1] = (short)s1; R.ent_g[idx + 1] = g1 * inv;
      }
    }
    __syncthreads();
    if (tid < 8) R.lbase[tid] = atomicAdd(&counts[tid], R.lcount[tid]);
    __syncthreads();
    if (tid < 128) {
      int e = R.ent_e[tid];
      int slot = R.lbase[e] + R.ent_slot[tid];
      int t = t0 + (tid >> 1);
      tlist[e * TT + slot] = t;
      glist[e * TT + slot] = R.ent_g[tid];
    }
    return;
  }

  // ---------------- transpose block ----------------
  TransSm& T = *reinterpret_cast<TransSm*>(smem);
  const int tb = bid - 128;
  const int job = tb / 4096;          // 0=Wg, 1=Wu, 2=Wd
  const int rem = tb - job * 4096;
  const int e = rem >> 9;             // /512
  const int xt = rem & 511;
  const float* src; int C, r0, c0;
  if (job < 2) {   // Wg/Wu: [H][I]
    src = (job ? Wu : Wg) + (size_t)e * HH * II;
    C = II; c0 = (xt & 31) * 64; r0 = (xt >> 5) * 64;
  } else {         // Wd: [I][H]
    src = Wd + (size_t)e * II * HH;
    C = HH; c0 = (xt & 15) * 64; r0 = (xt >> 4) * 64;
  }
  const int tx = tid & 15, ty = tid >> 4;
#pragma unroll
  for (int i = 0; i < 4; ++i) {
    int rr = i * 16 + ty;
    float4 v = *reinterpret_cast<const float4*>(&src[(size_t)(r0 + rr) * C + c0 + tx * 4]);
    T.tile[rr][tx * 4 + 0] = v.x; T.tile[rr][tx * 4 + 1] = v.y;
    T.tile[rr][tx * 4 + 2] = v.z; T.tile[rr][tx * 4 + 3] = v.w;
  }
  __syncthreads();
#pragma unroll
  for (int i = 0; i < 2; ++i) {
    int idx = i * 256 + tid;
    int cc = idx >> 3, ch = idx & 7;   // out-row cc, 16B chunk ch
    us8 o;
#pragma unroll
    for (int j = 0; j < 8; ++j) o[j] = f2bf(T.tile[ch * 8 + j][cc]);
    if (job < 2) {
      int srow = c0 * 2 + ((cc >> 4) << 5) + job * 16 + (cc & 15);
      *reinterpret_cast<us8*>(&WguT[((size_t)e * 2 * II + srow) * HH + r0 + ch * 8]) = o;
    } else {
      *reinterpret_cast<us8*>(&WdT[((size_t)e * HH + c0 + cc) * II + r0 + ch * 8]) = o;
    }
  }
}

// ---------------- GEMM1: 128x128 vs interleaved WguT ----------------
// R6/R8/R10-proven 2-barrier structure, 4 blocks/CU, grid x = N-tile fastest
// (same-B-column blocks land on one XCD: 32*dy%8==0; A spread across XCDs).
// Epilogue: acc[m][n] n even = gate, n+1 = up of SAME logical cols.
__global__ __launch_bounds__(256, 4) void k_gemm1(
    const unsigned short* __restrict__ xb,
    const unsigned short* __restrict__ WguT,
    const int* __restrict__ tlist, const float* __restrict__ glist,
    const int* __restrict__ counts,
    unsigned short* __restrict__ hbuf) {
  __shared__ unsigned short lsA[128 * 64];
  __shared__ unsigned short lsB[128 * 64];
  __shared__ int s_tok[128];
  __shared__ float s_gate[128];

  const int e = blockIdx.z;
  int n_e = 0, obase = 0;
#pragma unroll
  for (int q = 0; q < EE; ++q) {   // inline prefix (no k_offsets dispatch)
    int c = counts[q];
    if (q < e) obase += c;
    if (q == e) n_e = c;
  }
  const int row0 = blockIdx.y * 128;
  if (row0 >= n_e) return;
  const int n0 = blockIdx.x * 128;   // stored-row base in WguT
  const int tid = threadIdx.x;

  if (tid < 128) {
    int r = row0 + tid;
    int tok = 0; float gt = 0.f;
    if (r < n_e) { tok = tlist[e * TT + r]; gt = glist[e * TT + r]; }
    s_tok[tid] = tok; s_gate[tid] = gt;
  }
  __syncthreads();

  const int scol = (tid & 7) ^ ((tid >> 3) & 7);
  const unsigned short* srcA[4];
  const unsigned short* srcB[4];
#pragma unroll
  for (int i = 0; i < 4; ++i) {
    int row = i * 32 + (tid >> 3);
    srcA[i] = xb + (size_t)s_tok[row] * HH + scol * 8;
    srcB[i] = WguT + ((size_t)e * 2 * II + n0 + row) * HH + scol * 8;
  }

  f32x4 zero = {0.f, 0.f, 0.f, 0.f};
  f32x4 acc[4][4];
#pragma unroll
  for (int m = 0; m < 4; ++m)
#pragma unroll
    for (int n = 0; n < 4; ++n) acc[m][n] = zero;

  const int l = tid & 63;
  const int w = tid >> 6;
  const int wr = (w >> 1) * 64;
  const int wc = (w & 1) * 64;
  const int lrow = l & 15;
  const int lk = l >> 4;
  const int swz = (l & 7) << 4;
  const int aoff0 = (wr + lrow) * 128 + lk * 16;
  const int boff0 = (wc + lrow) * 128 + lk * 16;
  const char* lcA = (const char*)lsA;
  const char* lcB = (const char*)lsB;

  for (int kt = 0; kt < HH / 64; ++kt) {
#pragma unroll
    for (int i = 0; i < 4; ++i) {
      gload_lds16(srcA[i] + kt * 64, (char*)lsA + i * 4096 + tid * 16);
      gload_lds16(srcB[i] + kt * 64, (char*)lsB + i * 4096 + tid * 16);
    }
    __syncthreads();
#pragma unroll
    for (int kk = 0; kk < 2; ++kk) {
      bf16x8 af[4], bf[4];
#pragma unroll
      for (int m = 0; m < 4; ++m)
        af[m] = *(const bf16x8*)(lcA + ((aoff0 + m * 2048 + kk * 64) ^ swz));
#pragma unroll
      for (int n = 0; n < 4; ++n)
        bf[n] = *(const bf16x8*)(lcB + ((boff0 + n * 2048 + kk * 64) ^ swz));
#pragma unroll
      for (int m = 0; m < 4; ++m)
#pragma unroll
        for (int n = 0; n < 4; ++n)
          acc[m][n] = __builtin_amdgcn_mfma_f32_16x16x32_bf16(af[m], bf[n], acc[m][n], 0, 0, 0);
    }
    __syncthreads();
  }

#pragma unroll
  for (int m = 0; m < 4; ++m)
#pragma unroll
    for (int n = 0; n < 4; n += 2)   // n = gate frag, n+1 = up frag (same cols)
#pragma unroll
      for (int r = 0; r < 4; ++r) {
        int rl = wr + m * 16 + lk * 4 + r;   // C/D: col=lane&15, row=(lane>>4)*4+reg
        if (row0 + rl < n_e) {
          float gv = acc[m][n][r];
          float uv = acc[m][n + 1][r];
          float val = gv / (1.f + __expf(-gv)) * uv * s_gate[rl];
          int L = (n0 >> 1) + (wc >> 1) + (n >> 1) * 16 + lrow;   // logical II col
          hbuf[(size_t)(obase + row0 + rl) * II + L] = f2bf(val);
        }
      }
}

// ---------------- GEMM2: out += h @ Wd (atomic scatter; R8/R10 grid order) ----------------
__global__ __launch_bounds__(256, 4) void k_gemm2(
    const unsigned short* __restrict__ hbuf,
    const unsigned short* __restrict__ WdT,   // [E][H][I] (k=I contiguous)
    const int* __restrict__ tlist,
    const int* __restrict__ counts,
    float* __restrict__ out) {
  __shared__ unsigned short lsA[128 * 64];
  __shared__ unsigned short lsB[128 * 64];
  __shared__ int s_tok[128];

  const int e = blockIdx.z;
  int n_e = 0, obase = 0;
#pragma unroll
  for (int q = 0; q < EE; ++q) {
    int c = counts[q];
    if (q < e) obase += c;
    if (q == e) n_e = c;
  }
  const int row0 = blockIdx.y * 128;
  if (row0 >= n_e) return;
  const int n0 = blockIdx.x * 128;   // H columns
  const int tid = threadIdx.x;

  if (tid < 128) {
    int r = row0 + tid;
    s_tok[tid] = (r < n_e) ? tlist[e * TT + r] : 0;
  }
  __syncthreads();

  const int scol = (tid & 7) ^ ((tid >> 3) & 7);
  const unsigned short* srcA[4];
  const unsigned short* srcB[4];
#pragma unroll
  for (int i = 0; i < 4; ++i) {
    int row = i * 32 + (tid >> 3);
    int ar = obase + row0 + row;
    if (ar > TT * TOPK - 1) ar = TT * TOPK - 1;   // clamp pad rows inside hbuf
    srcA[i] = hbuf + (size_t)ar * II + scol * 8;
    srcB[i] = WdT + ((size_t)e * HH + n0 + row) * II + scol * 8;
  }

  f32x4 zero = {0.f, 0.f, 0.f, 0.f};
  f32x4 acc[4][4];
#pragma unroll
  for (int m = 0; m < 4; ++m)
#pragma unroll
    for (int n = 0; n < 4; ++n) acc[m][n] = zero;

  const int l = tid & 63;
  const int w = tid >> 6;
  const int wr = (w >> 1) * 64;
  const int wc = (w & 1) * 64;
  const int lrow = l & 15;
  const int lk = l >> 4;
  const int swz = (l & 7) << 4;
  const int aoff0 = (wr + lrow) * 128 + lk * 16;
  const int boff0 = (wc + lrow) * 128 + lk * 16;
  const char* lcA = (const char*)lsA;
  const char* lcB = (const char*)lsB;

  for (int kt = 0; kt < II / 64; ++kt) {
#pragma unroll
    for (int i = 0; i < 4; ++i) {
      gload_lds16(srcA[i] + kt * 64, (char*)lsA + i * 4096 + tid * 16);
      gload_lds16(srcB[i] + kt * 64, (char*)lsB + i * 4096 + tid * 16);
    }
    __syncthreads();
#pragma unroll
    for (int kk = 0; kk < 2; ++kk) {
      bf16x8 af[4], bf[4];
#pragma unroll
      for (int m = 0; m < 4; ++m)
        af[m] = *(const bf16x8*)(lcA + ((aoff0 + m * 2048 + kk * 64) ^ swz));
#pragma unroll
      for (int n = 0; n < 4; ++n)
        bf[n] = *(const bf16x8*)(lcB + ((boff0 + n * 2048 + kk * 64) ^ swz));
#pragma unroll
      for (int m = 0; m < 4; ++m)
#pragma unroll
        for (int n = 0; n < 4; ++n)
          acc[m][n] = __builtin_amdgcn_mfma_f32_16x16x32_bf16(af[m], bf[n], acc[m][n], 0, 0, 0);
    }
    __syncthreads();
  }

#pragma unroll
  for (int m = 0; m < 4; ++m)
#pragma unroll
    for (int n = 0; n < 4; ++n)
#pragma unroll
      for (int r = 0; r < 4; ++r) {
        int rl = wr + m * 16 + lk * 4 + r;
        if (row0 + rl < n_e) {
          int t = s_tok[rl];
          unsafeAtomicAdd(&out[(size_t)t * HH + n0 + wc + n * 16 + lrow], acc[m][n][r]);
        }
      }
}

extern "C" void kernel_launch(void* const* d_in, const int* in_sizes, int n_in,
                              void* d_out, int out_size, void* d_ws, size_t ws_size,
                              hipStream_t stream) {
  const float* x  = (const float*)d_in[0];
  const float* Wr = (const float*)d_in[1];
  const float* br = (const float*)d_in[2];
  const float* Wg = (const float*)d_in[3];
  const float* Wu = (const float*)d_in[4];
  const float* Wd = (const float*)d_in[5];
  float* out = (float*)d_out;

  char* ws = (char*)d_ws;
  size_t off = 0;
  auto alloc = [&](size_t bytes) {
    char* p = ws + off;
    off += (bytes + 255) & ~(size_t)255;
    return p;
  };
  unsigned short* xb   = (unsigned short*)alloc((size_t)TT * HH * 2);            // 16 MB
  unsigned short* WguT = (unsigned short*)alloc((size_t)EE * 2 * II * HH * 2);   // 64 MB
  unsigned short* WdT  = (unsigned short*)alloc((size_t)EE * HH * II * 2);       // 32 MB
  unsigned short* hbuf = (unsigned short*)alloc((size_t)TT * TOPK * II * 2);     // 64 MB
  int*   tlist  = (int*)alloc((size_t)EE * TT * 4);
  float* glist  = (float*)alloc((size_t)EE * TT * 4);
  int*   counts = (int*)alloc(128);

  hipMemsetAsync(counts, 0, 128, stream);

  // fused prep: router (blocks 0..127) + Wg/Wu/Wd transposes + d_out zeroing
  k_prep<<<128 + NTRANS + NZERO, 256, 0, stream>>>(x, Wr, br, Wg, Wu, Wd,
                                                   xb, WguT, WdT, tlist, glist,
                                                   counts, out);

  dim3 g1(2 * II / 128, TT / 128, EE);   // x = N-tile fastest (proven order)
  k_gemm1<<<g1, 256, 0, stream>>>(xb, WguT, tlist, glist, counts, hbuf);
  dim3 g2(HH / 128, TT / 128, EE);
  k_gemm2<<<g2, 256, 0, stream>>>(hbuf, WdT, tlist, counts, out);

  (void)in_sizes; (void)n_in; (void)out_size; (void)ws_size;
}